// Round 3
// baseline (949.799 us; speedup 1.0000x reference)
//
#include <hip/hip_runtime.h>
#include <hip/hip_bf16.h>
#include <math.h>

#define NH 4      // heads
#define OE 16     // OUT_E
#define ON 32     // OUT_N
#define INN 128   // IN_N
#define INE 32    // IN_E
#define HOE 64    // NH*OE
#define HON 128   // NH*ON

__device__ __forceinline__ float readlane_f(float v, int k) {
    return __uint_as_float(__builtin_amdgcn_readlane(__float_as_uint(v), k));
}

// ---------------- K0: zero int32 buffer ----------------
__global__ void k_zero_i32(int* __restrict__ p, int n) {
    int i = blockIdx.x * blockDim.x + threadIdx.x;
    int stride = gridDim.x * blockDim.x;
    for (; i < n; i += stride) p[i] = 0;
}

// ---------------- K1: fused node GEMM ----------------
__launch_bounds__(256, 2)
__global__ void k_node_gemm(const float* __restrict__ nf,
                            const float* __restrict__ Wni,
                            const float* __restrict__ Wnj,
                            const float* __restrict__ Wnode,
                            float* __restrict__ fni,
                            float* __restrict__ fnj,
                            float* __restrict__ hproj,
                            int Nn) {
    __shared__ float Alds[64][132];
    __shared__ float Wlds[128][64];
    int tid = threadIdx.x;
    int row0 = blockIdx.x * 64;
    #pragma unroll
    for (int t = 0; t < 8; t++) {
        int chunk = tid + t * 256;
        int r = chunk >> 5;
        int c4 = (chunk & 31) << 2;
        float4 v = make_float4(0.f, 0.f, 0.f, 0.f);
        int gr = row0 + r;
        if (gr < Nn) v = *(const float4*)&nf[(size_t)gr * INN + c4];
        Alds[r][c4 + 0] = v.x; Alds[r][c4 + 1] = v.y;
        Alds[r][c4 + 2] = v.z; Alds[r][c4 + 3] = v.w;
    }
    int tr = tid >> 4, tc = tid & 15;
    for (int p = 0; p < 4; p++) {
        const float* wsrc; int wstride, wcoff;
        float* dst; int dstride, dcoff;
        if (p == 0)      { wsrc = Wni;   wstride = 64;  wcoff = 0;  dst = fni;   dstride = 64;  dcoff = 0; }
        else if (p == 1) { wsrc = Wnj;   wstride = 64;  wcoff = 0;  dst = fnj;   dstride = 64;  dcoff = 0; }
        else if (p == 2) { wsrc = Wnode; wstride = 128; wcoff = 0;  dst = hproj; dstride = 128; dcoff = 0; }
        else             { wsrc = Wnode; wstride = 128; wcoff = 64; dst = hproj; dstride = 128; dcoff = 64; }
        __syncthreads();
        #pragma unroll
        for (int t = 0; t < 8; t++) {
            int chunk = tid + t * 256;
            int k = chunk >> 4;
            int c4 = (chunk & 15) << 2;
            float4 v = *(const float4*)&wsrc[(size_t)k * wstride + wcoff + c4];
            *(float4*)&Wlds[k][c4] = v;
        }
        __syncthreads();
        float acc[4][4];
        #pragma unroll
        for (int i = 0; i < 4; i++)
            #pragma unroll
            for (int j = 0; j < 4; j++) acc[i][j] = 0.f;
        for (int k = 0; k < 128; k++) {
            float4 b = *(float4*)&Wlds[k][tc << 2];
            #pragma unroll
            for (int i = 0; i < 4; i++) {
                float a = Alds[tr * 4 + i][k];
                acc[i][0] += a * b.x; acc[i][1] += a * b.y;
                acc[i][2] += a * b.z; acc[i][3] += a * b.w;
            }
        }
        #pragma unroll
        for (int i = 0; i < 4; i++) {
            int gr = row0 + tr * 4 + i;
            if (gr < Nn) {
                float4 v = make_float4(acc[i][0], acc[i][1], acc[i][2], acc[i][3]);
                *(float4*)&dst[(size_t)gr * dstride + dcoff + (tc << 2)] = v;
            }
        }
    }
}

// ---------------- K2: edge pass (wave per edge, scalarized uniforms) ---------
__launch_bounds__(256)
__global__ void k_edge(const float* __restrict__ efeats,
                       const int* __restrict__ src,
                       const int* __restrict__ dst,
                       const float* __restrict__ Wfij,   // [32][64]
                       const float* __restrict__ bias,   // [64]
                       const float* __restrict__ attn,   // [64]
                       const float* __restrict__ fni,
                       const float* __restrict__ fnj,
                       float* __restrict__ fout,         // [E,64]
                       float* __restrict__ exws,         // [E,4]
                       int* __restrict__ count,          // [N]
                       int Ee) {
    int tid = threadIdx.x;
    int lane = tid & 63;
    float wf[32];
    #pragma unroll
    for (int k = 0; k < 32; k++) wf[k] = Wfij[k * HOE + lane];
    float bi = bias[lane];
    float at = attn[lane];
    int wid = (blockIdx.x * 256 + tid) >> 6;
    int nw = (gridDim.x * 256) >> 6;
    for (int e0 = wid; e0 < Ee; e0 += nw) {
        // wave-uniform scalars: edge id, endpoints
        int e = __builtin_amdgcn_readfirstlane(e0);
        int s = __builtin_amdgcn_readfirstlane(src[e]);
        int d = __builtin_amdgcn_readfirstlane(dst[e]);
        const float* efp = efeats + (size_t)e * INE;
        float fv = fni[(size_t)s * HOE + lane] + fnj[(size_t)d * HOE + lane] + bi;
        float acc = 0.f;
        #pragma unroll
        for (int k = 0; k < 32; k += 4) {
            float4 t = *(const float4*)&efp[k];   // uniform address
            acc = fmaf(t.x, wf[k + 0], acc);
            acc = fmaf(t.y, wf[k + 1], acc);
            acc = fmaf(t.z, wf[k + 2], acc);
            acc = fmaf(t.w, wf[k + 3], acc);
        }
        fv += acc;
        fv = fv > 0.f ? fv : 0.01f * fv;                  // leaky relu
        fout[(size_t)e * HOE + lane] = fv;
        float pl = fv * at;
        #pragma unroll
        for (int o = 8; o >= 1; o >>= 1) pl += __shfl_xor(pl, o, 16);
        if ((lane & 15) == 0) exws[(size_t)e * NH + (lane >> 4)] = __expf(pl);
        if (lane == 0) atomicAdd(&count[d], 1);
    }
}

// ---------------- K3a: per-chunk exclusive scan (chunks of 256) --------------
__global__ void k_scan_chunks(const int* __restrict__ count,
                              int* __restrict__ chunkscan,
                              int* __restrict__ chunktot, int n) {
    __shared__ int tmp[256];
    int t = threadIdx.x;
    int i = blockIdx.x * 256 + t;
    int v = (i < n) ? count[i] : 0;
    tmp[t] = v;
    __syncthreads();
    for (int o = 1; o < 256; o <<= 1) {
        int x = (t >= o) ? tmp[t - o] : 0;
        __syncthreads();
        tmp[t] += x;
        __syncthreads();
    }
    if (i < n) chunkscan[i] = tmp[t] - v;
    if (t == 255) chunktot[blockIdx.x] = tmp[t];
}

// ---------------- K3b: scan chunk totals (single block) ----------------------
__global__ void k_scan_tot(const int* __restrict__ tot, int* __restrict__ base, int nc) {
    __shared__ int tmp[1024];
    int t = threadIdx.x;
    int v = (t < nc) ? tot[t] : 0;
    tmp[t] = v;
    __syncthreads();
    for (int o = 1; o < 1024; o <<= 1) {
        int x = (t >= o) ? tmp[t - o] : 0;
        __syncthreads();
        tmp[t] += x;
        __syncthreads();
    }
    if (t < nc) base[t] = tmp[t] - v;
}

// ---------------- K3c: final offsets ----------------------------------------
__global__ void k_offsets(const int* __restrict__ chunkscan,
                          const int* __restrict__ chunkbase,
                          int* __restrict__ offsets, int Nn, int Ee) {
    int i = blockIdx.x * blockDim.x + threadIdx.x;
    if (i < Nn) offsets[i] = chunkscan[i] + chunkbase[i >> 8];
    if (i == 0) offsets[Nn] = Ee;
}

// ---------------- K4: fill CSR edge lists ------------------------------------
__global__ void k_fill(const int* __restrict__ dst,
                       const int* __restrict__ offsets,
                       int* __restrict__ cursor,
                       int* __restrict__ eids, int Ee) {
    int i = blockIdx.x * blockDim.x + threadIdx.x;
    int stride = gridDim.x * blockDim.x;
    for (; i < Ee; i += stride) {
        int d = dst[i];
        int p = atomicAdd(&cursor[d], 1);
        eids[offsets[d] + p] = i;
    }
}

// ---------------- K5: node-centric softmax + aggregation (single pass) -------
__launch_bounds__(256)
__global__ void k_node_out(const int* __restrict__ offsets,
                           const int* __restrict__ eids,
                           const int* __restrict__ srcv,
                           const float* __restrict__ exws,   // [E,4]
                           const float* __restrict__ hproj,  // [N,128]
                           float* __restrict__ hout,         // [N,128]
                           int Nn) {
    int lane = threadIdx.x & 63;
    int n = (blockIdx.x * 256 + threadIdx.x) >> 6;
    if (n >= Nn) return;
    int o0 = offsets[n], o1 = offsets[n + 1];
    int hi = lane >> 5;
    float s0 = 0.f, s1 = 0.f, s2 = 0.f, s3 = 0.f;
    float a0 = 0.f, a1 = 0.f;
    for (int i0 = o0; i0 < o1; i0 += 64) {
        int nb = min(64, o1 - i0);
        int ve = 0, vs = 0;
        if (lane < nb) {
            ve = eids[i0 + lane];
            vs = srcv[ve];
        }
        for (int j = 0; j < nb; j++) {
            int e = __builtin_amdgcn_readlane(ve, j);
            int s = __builtin_amdgcn_readlane(vs, j);
            float4 x = *(const float4*)&exws[(size_t)e * NH];
            s0 += x.x; s1 += x.y; s2 += x.z; s3 += x.w;
            float exl = (hi == 0) ? x.x : x.y;
            float exh = (hi == 0) ? x.z : x.w;
            a0 += hproj[(size_t)s * HON + lane] * exl;
            a1 += hproj[(size_t)s * HON + 64 + lane] * exh;
        }
    }
    float r0 = s0 > 0.f ? 1.f / s0 : 0.f;
    float r1 = s1 > 0.f ? 1.f / s1 : 0.f;
    float r2 = s2 > 0.f ? 1.f / s2 : 0.f;
    float r3 = s3 > 0.f ? 1.f / s3 : 0.f;
    float rlo = (hi == 0) ? r0 : r1;
    float rhi = (hi == 0) ? r2 : r3;
    hout[(size_t)n * HON + lane] = a0 * rlo;
    hout[(size_t)n * HON + 64 + lane] = a1 * rhi;
}

// ---------------- launcher ----------------
extern "C" void kernel_launch(void* const* d_in, const int* in_sizes, int n_in,
                              void* d_out, int out_size, void* d_ws, size_t ws_size,
                              hipStream_t stream) {
    const float* n_feats = (const float*)d_in[0];
    const float* e_feats = (const float*)d_in[1];
    const int*   src     = (const int*)d_in[2];
    const int*   dst     = (const int*)d_in[3];
    const float* W_ni    = (const float*)d_in[4];
    const float* W_nj    = (const float*)d_in[5];
    const float* W_fij   = (const float*)d_in[6];
    const float* bias_e  = (const float*)d_in[7];
    const float* attn    = (const float*)d_in[8];
    const float* W_node  = (const float*)d_in[9];

    const int Nn = in_sizes[0] / INN;
    const int Ee = in_sizes[2];

    float* hout = (float*)d_out;                       // [N,128]
    float* fout = (float*)d_out + (size_t)Nn * HON;    // [E,64]

    char* ws = (char*)d_ws;
    size_t off = 0;
    auto alloc = [&](size_t bytes) {
        size_t o = off;
        off = (off + bytes + 255) & ~(size_t)255;
        return o;
    };
    size_t o_fni   = alloc((size_t)Nn * HOE * 4);
    size_t o_fnj   = alloc((size_t)Nn * HOE * 4);
    size_t o_hproj = alloc((size_t)Nn * HON * 4);
    size_t o_exws  = alloc((size_t)Ee * NH * 4);
    size_t o_eids  = alloc((size_t)Ee * 4);
    size_t o_cnt2  = alloc((size_t)2 * Nn * 4);        // count | cursor (contiguous)
    size_t o_offs  = alloc((size_t)(Nn + 1) * 4);
    size_t o_cscan = alloc((size_t)Nn * 4);
    size_t o_cbase = alloc((size_t)1024 * 4);
    (void)ws_size;

    float* fni   = (float*)(ws + o_fni);
    float* fnj   = (float*)(ws + o_fnj);
    float* hproj = (float*)(ws + o_hproj);
    float* exws  = (float*)(ws + o_exws);
    int* eids    = (int*)(ws + o_eids);
    int* cnt2    = (int*)(ws + o_cnt2);
    int* count   = cnt2;
    int* cursor  = cnt2 + Nn;
    int* offsets = (int*)(ws + o_offs);
    int* cscan   = (int*)(ws + o_cscan);
    int* cbase   = (int*)(ws + o_cbase);

    int nchunks = (Nn + 255) / 256;

    k_zero_i32<<<(2 * Nn + 255) / 256, 256, 0, stream>>>(cnt2, 2 * Nn);

    k_node_gemm<<<(Nn + 63) / 64, 256, 0, stream>>>(
        n_feats, W_ni, W_nj, W_node, fni, fnj, hproj, Nn);

    k_edge<<<8192, 256, 0, stream>>>(
        e_feats, src, dst, W_fij, bias_e, attn, fni, fnj, fout, exws, count, Ee);

    k_scan_chunks<<<nchunks, 256, 0, stream>>>(count, cscan, cbase, Nn);
    k_scan_tot<<<1, 1024, 0, stream>>>(cbase, cbase, nchunks);
    k_offsets<<<(Nn + 255) / 256, 256, 0, stream>>>(cscan, cbase, offsets, Nn, Ee);

    k_fill<<<4096, 256, 0, stream>>>(dst, offsets, cursor, eids, Ee);

    k_node_out<<<(Nn + 3) / 4, 256, 0, stream>>>(
        offsets, eids, src, exws, hproj, hout, Nn);
}

// Round 4
// 833.881 us; speedup vs baseline: 1.1390x; 1.1390x over previous
//
#include <hip/hip_runtime.h>
#include <hip/hip_bf16.h>
#include <math.h>

#define NH 4      // heads
#define OE 16     // OUT_E
#define ON 32     // OUT_N
#define INN 128   // IN_N
#define INE 32    // IN_E
#define HOE 64    // NH*OE
#define HON 128   // NH*ON

// ---------------- K0: zero int32 buffer ----------------
__global__ void k_zero_i32(int* __restrict__ p, int n) {
    int i = blockIdx.x * blockDim.x + threadIdx.x;
    int stride = gridDim.x * blockDim.x;
    for (; i < n; i += stride) p[i] = 0;
}

// ---------------- K1: fused node GEMM ----------------
__launch_bounds__(256, 2)
__global__ void k_node_gemm(const float* __restrict__ nf,
                            const float* __restrict__ Wni,
                            const float* __restrict__ Wnj,
                            const float* __restrict__ Wnode,
                            float* __restrict__ fni,
                            float* __restrict__ fnj,
                            float* __restrict__ hproj,
                            int Nn) {
    __shared__ float Alds[64][132];
    __shared__ float Wlds[128][64];
    int tid = threadIdx.x;
    int row0 = blockIdx.x * 64;
    #pragma unroll
    for (int t = 0; t < 8; t++) {
        int chunk = tid + t * 256;
        int r = chunk >> 5;
        int c4 = (chunk & 31) << 2;
        float4 v = make_float4(0.f, 0.f, 0.f, 0.f);
        int gr = row0 + r;
        if (gr < Nn) v = *(const float4*)&nf[(size_t)gr * INN + c4];
        Alds[r][c4 + 0] = v.x; Alds[r][c4 + 1] = v.y;
        Alds[r][c4 + 2] = v.z; Alds[r][c4 + 3] = v.w;
    }
    int tr = tid >> 4, tc = tid & 15;
    for (int p = 0; p < 4; p++) {
        const float* wsrc; int wstride, wcoff;
        float* dst; int dstride, dcoff;
        if (p == 0)      { wsrc = Wni;   wstride = 64;  wcoff = 0;  dst = fni;   dstride = 64;  dcoff = 0; }
        else if (p == 1) { wsrc = Wnj;   wstride = 64;  wcoff = 0;  dst = fnj;   dstride = 64;  dcoff = 0; }
        else if (p == 2) { wsrc = Wnode; wstride = 128; wcoff = 0;  dst = hproj; dstride = 128; dcoff = 0; }
        else             { wsrc = Wnode; wstride = 128; wcoff = 64; dst = hproj; dstride = 128; dcoff = 64; }
        __syncthreads();
        #pragma unroll
        for (int t = 0; t < 8; t++) {
            int chunk = tid + t * 256;
            int k = chunk >> 4;
            int c4 = (chunk & 15) << 2;
            float4 v = *(const float4*)&wsrc[(size_t)k * wstride + wcoff + c4];
            *(float4*)&Wlds[k][c4] = v;
        }
        __syncthreads();
        float acc[4][4];
        #pragma unroll
        for (int i = 0; i < 4; i++)
            #pragma unroll
            for (int j = 0; j < 4; j++) acc[i][j] = 0.f;
        for (int k = 0; k < 128; k++) {
            float4 b = *(float4*)&Wlds[k][tc << 2];
            #pragma unroll
            for (int i = 0; i < 4; i++) {
                float a = Alds[tr * 4 + i][k];
                acc[i][0] += a * b.x; acc[i][1] += a * b.y;
                acc[i][2] += a * b.z; acc[i][3] += a * b.w;
            }
        }
        #pragma unroll
        for (int i = 0; i < 4; i++) {
            int gr = row0 + tr * 4 + i;
            if (gr < Nn) {
                float4 v = make_float4(acc[i][0], acc[i][1], acc[i][2], acc[i][3]);
                *(float4*)&dst[(size_t)gr * dstride + dcoff + (tc << 2)] = v;
            }
        }
    }
}

// ---------------- K2: edge pass (wave per edge, LDS-broadcast ef) ------------
__launch_bounds__(256)
__global__ void k_edge(const float* __restrict__ efeats,
                       const int* __restrict__ src,
                       const int* __restrict__ dst,
                       const float* __restrict__ Wfij,   // [32][64]
                       const float* __restrict__ bias,   // [64]
                       const float* __restrict__ attn,   // [64]
                       const float* __restrict__ fni,
                       const float* __restrict__ fnj,
                       float* __restrict__ fout,         // [E,64]
                       float* __restrict__ exws,         // [E,4]
                       int* __restrict__ count,          // [N]
                       int Ee) {
    __shared__ float efs[4][64];     // per-wave private slot (wave-coherent, no barrier)
    int tid = threadIdx.x;
    int lane = tid & 63;
    int w = tid >> 6;
    float wf[32];
    #pragma unroll
    for (int k = 0; k < 32; k++) wf[k] = Wfij[k * HOE + lane];
    float bi = bias[lane];
    float at = attn[lane];
    int wid = (blockIdx.x * 256 + tid) >> 6;
    int nw = (gridDim.x * 256) >> 6;
    for (int e = wid; e < Ee; e += nw) {
        int s = src[e], d = dst[e];                       // uniform-address vector loads
        float ef = efeats[(size_t)e * INE + (lane & 31)]; // one 128B fetch per wave
        efs[w][lane] = ef;                                // stage row for broadcast
        float fv = fni[(size_t)s * HOE + lane] + fnj[(size_t)d * HOE + lane] + bi;
        float acc = 0.f;
        #pragma unroll
        for (int k = 0; k < 32; k += 4) {
            float4 t = *(const float4*)&efs[w][k];        // uniform LDS broadcast read
            acc = fmaf(t.x, wf[k + 0], acc);
            acc = fmaf(t.y, wf[k + 1], acc);
            acc = fmaf(t.z, wf[k + 2], acc);
            acc = fmaf(t.w, wf[k + 3], acc);
        }
        fv += acc;
        fv = fv > 0.f ? fv : 0.01f * fv;                  // leaky relu
        fout[(size_t)e * HOE + lane] = fv;
        float pl = fv * at;
        #pragma unroll
        for (int o = 8; o >= 1; o >>= 1) pl += __shfl_xor(pl, o, 16);
        if ((lane & 15) == 0) exws[(size_t)e * NH + (lane >> 4)] = __expf(pl);
        if (lane == 0) atomicAdd(&count[d], 1);
    }
}

// ---------------- K3a: per-chunk exclusive scan (chunks of 256) --------------
__global__ void k_scan_chunks(const int* __restrict__ count,
                              int* __restrict__ chunkscan,
                              int* __restrict__ chunktot, int n) {
    __shared__ int tmp[256];
    int t = threadIdx.x;
    int i = blockIdx.x * 256 + t;
    int v = (i < n) ? count[i] : 0;
    tmp[t] = v;
    __syncthreads();
    for (int o = 1; o < 256; o <<= 1) {
        int x = (t >= o) ? tmp[t - o] : 0;
        __syncthreads();
        tmp[t] += x;
        __syncthreads();
    }
    if (i < n) chunkscan[i] = tmp[t] - v;
    if (t == 255) chunktot[blockIdx.x] = tmp[t];
}

// ---------------- K3b: scan chunk totals (single block) ----------------------
__global__ void k_scan_tot(const int* __restrict__ tot, int* __restrict__ base, int nc) {
    __shared__ int tmp[1024];
    int t = threadIdx.x;
    int v = (t < nc) ? tot[t] : 0;
    tmp[t] = v;
    __syncthreads();
    for (int o = 1; o < 1024; o <<= 1) {
        int x = (t >= o) ? tmp[t - o] : 0;
        __syncthreads();
        tmp[t] += x;
        __syncthreads();
    }
    if (t < nc) base[t] = tmp[t] - v;
}

// ---------------- K3c: final offsets ----------------------------------------
__global__ void k_offsets(const int* __restrict__ chunkscan,
                          const int* __restrict__ chunkbase,
                          int* __restrict__ offsets, int Nn, int Ee) {
    int i = blockIdx.x * blockDim.x + threadIdx.x;
    if (i < Nn) offsets[i] = chunkscan[i] + chunkbase[i >> 8];
    if (i == 0) offsets[Nn] = Ee;
}

// ---------------- K4: fill CSR edge lists ------------------------------------
__global__ void k_fill(const int* __restrict__ dst,
                       const int* __restrict__ offsets,
                       int* __restrict__ cursor,
                       int* __restrict__ eids, int Ee) {
    int i = blockIdx.x * blockDim.x + threadIdx.x;
    int stride = gridDim.x * blockDim.x;
    for (; i < Ee; i += stride) {
        int d = dst[i];
        int p = atomicAdd(&cursor[d], 1);
        eids[offsets[d] + p] = i;
    }
}

// ---------------- K5: node-centric softmax + aggregation (single pass) -------
__launch_bounds__(256)
__global__ void k_node_out(const int* __restrict__ offsets,
                           const int* __restrict__ eids,
                           const int* __restrict__ srcv,
                           const float* __restrict__ exws,   // [E,4]
                           const float* __restrict__ hproj,  // [N,128]
                           float* __restrict__ hout,         // [N,128]
                           int Nn) {
    int lane = threadIdx.x & 63;
    int n = (blockIdx.x * 256 + threadIdx.x) >> 6;
    if (n >= Nn) return;
    int o0 = offsets[n], o1 = offsets[n + 1];
    int hi = lane >> 5;
    float s0 = 0.f, s1 = 0.f, s2 = 0.f, s3 = 0.f;
    float a0 = 0.f, a1 = 0.f;
    for (int i0 = o0; i0 < o1; i0 += 64) {
        int nb = min(64, o1 - i0);
        int ve = 0, vs = 0;
        if (lane < nb) {
            ve = eids[i0 + lane];
            vs = srcv[ve];
        }
        for (int j = 0; j < nb; j++) {
            int e = __builtin_amdgcn_readlane(ve, j);
            int s = __builtin_amdgcn_readlane(vs, j);
            float4 x = *(const float4*)&exws[(size_t)e * NH];
            s0 += x.x; s1 += x.y; s2 += x.z; s3 += x.w;
            float exl = (hi == 0) ? x.x : x.y;
            float exh = (hi == 0) ? x.z : x.w;
            a0 += hproj[(size_t)s * HON + lane] * exl;
            a1 += hproj[(size_t)s * HON + 64 + lane] * exh;
        }
    }
    float r0 = s0 > 0.f ? 1.f / s0 : 0.f;
    float r1 = s1 > 0.f ? 1.f / s1 : 0.f;
    float r2 = s2 > 0.f ? 1.f / s2 : 0.f;
    float r3 = s3 > 0.f ? 1.f / s3 : 0.f;
    float rlo = (hi == 0) ? r0 : r1;
    float rhi = (hi == 0) ? r2 : r3;
    hout[(size_t)n * HON + lane] = a0 * rlo;
    hout[(size_t)n * HON + 64 + lane] = a1 * rhi;
}

// ---------------- launcher ----------------
extern "C" void kernel_launch(void* const* d_in, const int* in_sizes, int n_in,
                              void* d_out, int out_size, void* d_ws, size_t ws_size,
                              hipStream_t stream) {
    const float* n_feats = (const float*)d_in[0];
    const float* e_feats = (const float*)d_in[1];
    const int*   src     = (const int*)d_in[2];
    const int*   dst     = (const int*)d_in[3];
    const float* W_ni    = (const float*)d_in[4];
    const float* W_nj    = (const float*)d_in[5];
    const float* W_fij   = (const float*)d_in[6];
    const float* bias_e  = (const float*)d_in[7];
    const float* attn    = (const float*)d_in[8];
    const float* W_node  = (const float*)d_in[9];

    const int Nn = in_sizes[0] / INN;
    const int Ee = in_sizes[2];

    float* hout = (float*)d_out;                       // [N,128]
    float* fout = (float*)d_out + (size_t)Nn * HON;    // [E,64]

    char* ws = (char*)d_ws;
    size_t off = 0;
    auto alloc = [&](size_t bytes) {
        size_t o = off;
        off = (off + bytes + 255) & ~(size_t)255;
        return o;
    };
    size_t o_fni   = alloc((size_t)Nn * HOE * 4);
    size_t o_fnj   = alloc((size_t)Nn * HOE * 4);
    size_t o_hproj = alloc((size_t)Nn * HON * 4);
    size_t o_exws  = alloc((size_t)Ee * NH * 4);
    size_t o_eids  = alloc((size_t)Ee * 4);
    size_t o_cnt2  = alloc((size_t)2 * Nn * 4);        // count | cursor (contiguous)
    size_t o_offs  = alloc((size_t)(Nn + 1) * 4);
    size_t o_cscan = alloc((size_t)Nn * 4);
    size_t o_cbase = alloc((size_t)1024 * 4);
    (void)ws_size;

    float* fni   = (float*)(ws + o_fni);
    float* fnj   = (float*)(ws + o_fnj);
    float* hproj = (float*)(ws + o_hproj);
    float* exws  = (float*)(ws + o_exws);
    int* eids    = (int*)(ws + o_eids);
    int* cnt2    = (int*)(ws + o_cnt2);
    int* count   = cnt2;
    int* cursor  = cnt2 + Nn;
    int* offsets = (int*)(ws + o_offs);
    int* cscan   = (int*)(ws + o_cscan);
    int* cbase   = (int*)(ws + o_cbase);

    int nchunks = (Nn + 255) / 256;

    k_zero_i32<<<(2 * Nn + 255) / 256, 256, 0, stream>>>(cnt2, 2 * Nn);

    k_node_gemm<<<(Nn + 63) / 64, 256, 0, stream>>>(
        n_feats, W_ni, W_nj, W_node, fni, fnj, hproj, Nn);

    k_edge<<<8192, 256, 0, stream>>>(
        e_feats, src, dst, W_fij, bias_e, attn, fni, fnj, fout, exws, count, Ee);

    k_scan_chunks<<<nchunks, 256, 0, stream>>>(count, cscan, cbase, Nn);
    k_scan_tot<<<1, 1024, 0, stream>>>(cbase, cbase, nchunks);
    k_offsets<<<(Nn + 255) / 256, 256, 0, stream>>>(cscan, cbase, offsets, Nn, Ee);

    k_fill<<<4096, 256, 0, stream>>>(dst, offsets, cursor, eids, Ee);

    k_node_out<<<(Nn + 3) / 4, 256, 0, stream>>>(
        offsets, eids, src, exws, hproj, hout, Nn);
}

// Round 5
// 703.195 us; speedup vs baseline: 1.3507x; 1.1858x over previous
//
#include <hip/hip_runtime.h>
#include <hip/hip_bf16.h>
#include <math.h>

#define NH 4      // heads
#define OE 16     // OUT_E
#define ON 32     // OUT_N
#define INN 128   // IN_N
#define INE 32    // IN_E
#define HOE 64    // NH*OE
#define HON 128   // NH*ON

typedef __attribute__((ext_vector_type(8))) short bf16x8;
typedef __attribute__((ext_vector_type(4))) float f32x4;

__device__ __forceinline__ unsigned cvt_pk_bf16(float lo, float hi) {
    unsigned r;
    asm volatile("v_cvt_pk_bf16_f32 %0, %1, %2" : "=v"(r) : "v"(lo), "v"(hi));
    return r;
}

// ---------------- K0: zero int32 buffer ----------------
__global__ void k_zero_i32(int* __restrict__ p, int n) {
    int i = blockIdx.x * blockDim.x + threadIdx.x;
    int stride = gridDim.x * blockDim.x;
    for (; i < n; i += stride) p[i] = 0;
}

// ---------------- K1: fused node GEMM ----------------
__launch_bounds__(256, 2)
__global__ void k_node_gemm(const float* __restrict__ nf,
                            const float* __restrict__ Wni,
                            const float* __restrict__ Wnj,
                            const float* __restrict__ Wnode,
                            float* __restrict__ fni,
                            float* __restrict__ fnj,
                            float* __restrict__ hproj,
                            int Nn) {
    __shared__ float Alds[64][132];
    __shared__ float Wlds[128][64];
    int tid = threadIdx.x;
    int row0 = blockIdx.x * 64;
    #pragma unroll
    for (int t = 0; t < 8; t++) {
        int chunk = tid + t * 256;
        int r = chunk >> 5;
        int c4 = (chunk & 31) << 2;
        float4 v = make_float4(0.f, 0.f, 0.f, 0.f);
        int gr = row0 + r;
        if (gr < Nn) v = *(const float4*)&nf[(size_t)gr * INN + c4];
        Alds[r][c4 + 0] = v.x; Alds[r][c4 + 1] = v.y;
        Alds[r][c4 + 2] = v.z; Alds[r][c4 + 3] = v.w;
    }
    int tr = tid >> 4, tc = tid & 15;
    for (int p = 0; p < 4; p++) {
        const float* wsrc; int wstride, wcoff;
        float* dst; int dstride, dcoff;
        if (p == 0)      { wsrc = Wni;   wstride = 64;  wcoff = 0;  dst = fni;   dstride = 64;  dcoff = 0; }
        else if (p == 1) { wsrc = Wnj;   wstride = 64;  wcoff = 0;  dst = fnj;   dstride = 64;  dcoff = 0; }
        else if (p == 2) { wsrc = Wnode; wstride = 128; wcoff = 0;  dst = hproj; dstride = 128; dcoff = 0; }
        else             { wsrc = Wnode; wstride = 128; wcoff = 64; dst = hproj; dstride = 128; dcoff = 64; }
        __syncthreads();
        #pragma unroll
        for (int t = 0; t < 8; t++) {
            int chunk = tid + t * 256;
            int k = chunk >> 4;
            int c4 = (chunk & 15) << 2;
            float4 v = *(const float4*)&wsrc[(size_t)k * wstride + wcoff + c4];
            *(float4*)&Wlds[k][c4] = v;
        }
        __syncthreads();
        float acc[4][4];
        #pragma unroll
        for (int i = 0; i < 4; i++)
            #pragma unroll
            for (int j = 0; j < 4; j++) acc[i][j] = 0.f;
        for (int k = 0; k < 128; k++) {
            float4 b = *(float4*)&Wlds[k][tc << 2];
            #pragma unroll
            for (int i = 0; i < 4; i++) {
                float a = Alds[tr * 4 + i][k];
                acc[i][0] += a * b.x; acc[i][1] += a * b.y;
                acc[i][2] += a * b.z; acc[i][3] += a * b.w;
            }
        }
        #pragma unroll
        for (int i = 0; i < 4; i++) {
            int gr = row0 + tr * 4 + i;
            if (gr < Nn) {
                float4 v = make_float4(acc[i][0], acc[i][1], acc[i][2], acc[i][3]);
                *(float4*)&dst[(size_t)gr * dstride + dcoff + (tc << 2)] = v;
            }
        }
    }
}

// ---------------- K2: edge pass — MFMA for e_feats @ W_fij -------------------
// One wave handles 16 edges. A = ef[16x32] (bf16), B = W_fij[32x64] as 4 tiles.
// Layouts (m89-verified family): A: lane&15=row, k=(lane>>4)*8+i;
// B: lane&15=col, k=(lane>>4)*8+i; C: col=lane&15, row=(lane>>4)*4+reg.
__launch_bounds__(256)
__global__ void k_edge(const float* __restrict__ efeats,
                       const int* __restrict__ src,
                       const int* __restrict__ dst,
                       const float* __restrict__ Wfij,   // [32][64]
                       const float* __restrict__ bias,   // [64]
                       const float* __restrict__ attn,   // [64]
                       const float* __restrict__ fni,
                       const float* __restrict__ fnj,
                       float* __restrict__ fout,         // [E,64]
                       float* __restrict__ exws,         // [E,4]
                       int* __restrict__ count,          // [N]
                       int Ee) {
    int tid = threadIdx.x;
    int lane = tid & 63;
    int m = lane & 15;        // A row / B col / C col
    int kq = lane >> 4;       // k-quarter: k = kq*8 + i
    // B fragments (one-time): bv[t] = W_fij k-slice for output cols t*16..t*16+15
    bf16x8 bv[4];
    #pragma unroll
    for (int t = 0; t < 4; t++) {
        unsigned* bw = (unsigned*)&bv[t];
        #pragma unroll
        for (int i = 0; i < 4; i++) {
            float lo = Wfij[(kq * 8 + 2 * i) * HOE + t * 16 + m];
            float hi = Wfij[(kq * 8 + 2 * i + 1) * HOE + t * 16 + m];
            bw[i] = cvt_pk_bf16(lo, hi);
        }
    }
    float bb[4], aa[4];
    #pragma unroll
    for (int t = 0; t < 4; t++) { bb[t] = bias[t * 16 + m]; aa[t] = attn[t * 16 + m]; }

    int wid = (blockIdx.x * 256 + tid) >> 6;
    int nw = (gridDim.x * 256) >> 6;
    for (int e0 = wid * 16; e0 < Ee; e0 += nw * 16) {
        // A fragment: lane reads 8 consecutive ef floats of row e0+m at col kq*8
        int ea = e0 + m; if (ea >= Ee) ea = Ee - 1;
        const float* ap = &efeats[(size_t)ea * INE + kq * 8];
        float4 a0 = *(const float4*)ap;
        float4 a1 = *(const float4*)(ap + 4);
        bf16x8 av;
        {
            unsigned* aw = (unsigned*)&av;
            aw[0] = cvt_pk_bf16(a0.x, a0.y);
            aw[1] = cvt_pk_bf16(a0.z, a0.w);
            aw[2] = cvt_pk_bf16(a1.x, a1.y);
            aw[3] = cvt_pk_bf16(a1.z, a1.w);
        }
        f32x4 c[4];
        #pragma unroll
        for (int t = 0; t < 4; t++) {
            c[t] = __builtin_amdgcn_mfma_f32_16x16x32_bf16(av, bv[t], (f32x4){0.f,0.f,0.f,0.f}, 0, 0, 0);
        }
        // epilogue: 4 edges per lane (rows), cols m+16t
        #pragma unroll
        for (int j = 0; j < 4; j++) {
            int eq = e0 + kq * 4 + j;
            bool ok = eq < Ee;
            int ec = ok ? eq : (Ee - 1);
            int sj = src[ec], dj = dst[ec];
            const float* fnis = &fni[(size_t)sj * HOE];
            const float* fnjs = &fnj[(size_t)dj * HOE];
            #pragma unroll
            for (int t = 0; t < 4; t++) {
                int col = t * 16 + m;
                float fv = c[t][j] + fnis[col] + fnjs[col] + bb[t];
                fv = fv > 0.f ? fv : 0.01f * fv;          // leaky relu
                if (ok) fout[(size_t)eq * HOE + col] = fv;
                float pl = fv * aa[t];
                #pragma unroll
                for (int o = 8; o >= 1; o >>= 1) pl += __shfl_xor(pl, o, 16);
                if (ok && m == 0) exws[(size_t)eq * NH + t] = __expf(pl);
            }
            if (ok && m == 0) atomicAdd(&count[dj], 1);
        }
    }
}

// ---------------- K3a: per-chunk exclusive scan (chunks of 256) --------------
__global__ void k_scan_chunks(const int* __restrict__ count,
                              int* __restrict__ chunkscan,
                              int* __restrict__ chunktot, int n) {
    __shared__ int tmp[256];
    int t = threadIdx.x;
    int i = blockIdx.x * 256 + t;
    int v = (i < n) ? count[i] : 0;
    tmp[t] = v;
    __syncthreads();
    for (int o = 1; o < 256; o <<= 1) {
        int x = (t >= o) ? tmp[t - o] : 0;
        __syncthreads();
        tmp[t] += x;
        __syncthreads();
    }
    if (i < n) chunkscan[i] = tmp[t] - v;
    if (t == 255) chunktot[blockIdx.x] = tmp[t];
}

// ---------------- K3b: scan chunk totals (single block) ----------------------
__global__ void k_scan_tot(const int* __restrict__ tot, int* __restrict__ base, int nc) {
    __shared__ int tmp[1024];
    int t = threadIdx.x;
    int v = (t < nc) ? tot[t] : 0;
    tmp[t] = v;
    __syncthreads();
    for (int o = 1; o < 1024; o <<= 1) {
        int x = (t >= o) ? tmp[t - o] : 0;
        __syncthreads();
        tmp[t] += x;
        __syncthreads();
    }
    if (t < nc) base[t] = tmp[t] - v;
}

// ---------------- K3c: final offsets ----------------------------------------
__global__ void k_offsets(const int* __restrict__ chunkscan,
                          const int* __restrict__ chunkbase,
                          int* __restrict__ offsets, int Nn, int Ee) {
    int i = blockIdx.x * blockDim.x + threadIdx.x;
    if (i < Nn) offsets[i] = chunkscan[i] + chunkbase[i >> 8];
    if (i == 0) offsets[Nn] = Ee;
}

// ---------------- K4: fill CSR edge lists ------------------------------------
__global__ void k_fill(const int* __restrict__ dst,
                       const int* __restrict__ offsets,
                       int* __restrict__ cursor,
                       int* __restrict__ eids, int Ee) {
    int i = blockIdx.x * blockDim.x + threadIdx.x;
    int stride = gridDim.x * blockDim.x;
    for (; i < Ee; i += stride) {
        int d = dst[i];
        int p = atomicAdd(&cursor[d], 1);
        eids[offsets[d] + p] = i;
    }
}

// ---------------- K5: node-centric softmax + aggregation (single pass) -------
__launch_bounds__(256)
__global__ void k_node_out(const int* __restrict__ offsets,
                           const int* __restrict__ eids,
                           const int* __restrict__ srcv,
                           const float* __restrict__ exws,   // [E,4]
                           const float* __restrict__ hproj,  // [N,128]
                           float* __restrict__ hout,         // [N,128]
                           int Nn) {
    int lane = threadIdx.x & 63;
    int n = (blockIdx.x * 256 + threadIdx.x) >> 6;
    if (n >= Nn) return;
    int o0 = offsets[n], o1 = offsets[n + 1];
    int hi = lane >> 5;
    float s0 = 0.f, s1 = 0.f, s2 = 0.f, s3 = 0.f;
    float a0 = 0.f, a1 = 0.f;
    for (int i0 = o0; i0 < o1; i0 += 64) {
        int nb = min(64, o1 - i0);
        int ve = 0, vs = 0;
        if (lane < nb) {
            ve = eids[i0 + lane];
            vs = srcv[ve];
        }
        for (int j = 0; j < nb; j++) {
            int e = __builtin_amdgcn_readlane(ve, j);
            int s = __builtin_amdgcn_readlane(vs, j);
            float4 x = *(const float4*)&exws[(size_t)e * NH];
            s0 += x.x; s1 += x.y; s2 += x.z; s3 += x.w;
            float exl = (hi == 0) ? x.x : x.y;
            float exh = (hi == 0) ? x.z : x.w;
            a0 += hproj[(size_t)s * HON + lane] * exl;
            a1 += hproj[(size_t)s * HON + 64 + lane] * exh;
        }
    }
    float r0 = s0 > 0.f ? 1.f / s0 : 0.f;
    float r1 = s1 > 0.f ? 1.f / s1 : 0.f;
    float r2 = s2 > 0.f ? 1.f / s2 : 0.f;
    float r3 = s3 > 0.f ? 1.f / s3 : 0.f;
    float rlo = (hi == 0) ? r0 : r1;
    float rhi = (hi == 0) ? r2 : r3;
    hout[(size_t)n * HON + lane] = a0 * rlo;
    hout[(size_t)n * HON + 64 + lane] = a1 * rhi;
}

// ---------------- launcher ----------------
extern "C" void kernel_launch(void* const* d_in, const int* in_sizes, int n_in,
                              void* d_out, int out_size, void* d_ws, size_t ws_size,
                              hipStream_t stream) {
    const float* n_feats = (const float*)d_in[0];
    const float* e_feats = (const float*)d_in[1];
    const int*   src     = (const int*)d_in[2];
    const int*   dst     = (const int*)d_in[3];
    const float* W_ni    = (const float*)d_in[4];
    const float* W_nj    = (const float*)d_in[5];
    const float* W_fij   = (const float*)d_in[6];
    const float* bias_e  = (const float*)d_in[7];
    const float* attn    = (const float*)d_in[8];
    const float* W_node  = (const float*)d_in[9];

    const int Nn = in_sizes[0] / INN;
    const int Ee = in_sizes[2];

    float* hout = (float*)d_out;                       // [N,128]
    float* fout = (float*)d_out + (size_t)Nn * HON;    // [E,64]

    char* ws = (char*)d_ws;
    size_t off = 0;
    auto alloc = [&](size_t bytes) {
        size_t o = off;
        off = (off + bytes + 255) & ~(size_t)255;
        return o;
    };
    size_t o_fni   = alloc((size_t)Nn * HOE * 4);
    size_t o_fnj   = alloc((size_t)Nn * HOE * 4);
    size_t o_hproj = alloc((size_t)Nn * HON * 4);
    size_t o_exws  = alloc((size_t)Ee * NH * 4);
    size_t o_eids  = alloc((size_t)Ee * 4);
    size_t o_cnt2  = alloc((size_t)2 * Nn * 4);        // count | cursor
    size_t o_offs  = alloc((size_t)(Nn + 1) * 4);
    size_t o_cscan = alloc((size_t)Nn * 4);
    size_t o_cbase = alloc((size_t)1024 * 4);
    (void)ws_size;

    float* fni   = (float*)(ws + o_fni);
    float* fnj   = (float*)(ws + o_fnj);
    float* hproj = (float*)(ws + o_hproj);
    float* exws  = (float*)(ws + o_exws);
    int* eids    = (int*)(ws + o_eids);
    int* cnt2    = (int*)(ws + o_cnt2);
    int* count   = cnt2;
    int* cursor  = cnt2 + Nn;
    int* offsets = (int*)(ws + o_offs);
    int* cscan   = (int*)(ws + o_cscan);
    int* cbase   = (int*)(ws + o_cbase);

    int nchunks = (Nn + 255) / 256;

    k_zero_i32<<<(2 * Nn + 255) / 256, 256, 0, stream>>>(cnt2, 2 * Nn);

    k_node_gemm<<<(Nn + 63) / 64, 256, 0, stream>>>(
        n_feats, W_ni, W_nj, W_node, fni, fnj, hproj, Nn);

    k_edge<<<8192, 256, 0, stream>>>(
        e_feats, src, dst, W_fij, bias_e, attn, fni, fnj, fout, exws, count, Ee);

    k_scan_chunks<<<nchunks, 256, 0, stream>>>(count, cscan, cbase, Nn);
    k_scan_tot<<<1, 1024, 0, stream>>>(cbase, cbase, nchunks);
    k_offsets<<<(Nn + 255) / 256, 256, 0, stream>>>(cscan, cbase, offsets, Nn, Ee);

    k_fill<<<4096, 256, 0, stream>>>(dst, offsets, cursor, eids, Ee);

    k_node_out<<<(Nn + 3) / 4, 256, 0, stream>>>(
        offsets, eids, src, exws, hproj, hout, Nn);
}

// Round 6
// 642.368 us; speedup vs baseline: 1.4786x; 1.0947x over previous
//
#include <hip/hip_runtime.h>
#include <hip/hip_bf16.h>
#include <math.h>

#define NH 4      // heads
#define OE 16     // OUT_E
#define ON 32     // OUT_N
#define INN 128   // IN_N
#define INE 32    // IN_E
#define HOE 64    // NH*OE
#define HON 128   // NH*ON

typedef __attribute__((ext_vector_type(8))) short bf16x8;
typedef __attribute__((ext_vector_type(4))) float f32x4;

__device__ __forceinline__ unsigned cvt_pk_bf16(float lo, float hi) {
    unsigned r;
    asm volatile("v_cvt_pk_bf16_f32 %0, %1, %2" : "=v"(r) : "v"(lo), "v"(hi));
    return r;
}

// ---------------- K0: zero int32 buffer ----------------
__global__ void k_zero_i32(int* __restrict__ p, int n) {
    int i = blockIdx.x * blockDim.x + threadIdx.x;
    int stride = gridDim.x * blockDim.x;
    for (; i < n; i += stride) p[i] = 0;
}

// ---------------- K0b: degree count ----------------
__global__ void k_count(const int* __restrict__ dst, int* __restrict__ count, int Ee) {
    int i = blockIdx.x * blockDim.x + threadIdx.x;
    int stride = gridDim.x * blockDim.x;
    for (; i < Ee; i += stride) atomicAdd(&count[dst[i]], 1);
}

// ---------------- K1: fused node GEMM via MFMA -------------------------------
// Each block: 4 waves, all cover the same 16 rows; wave w produces one 64-col
// output slice {fni, fnj, hproj[0:64], hproj[64:128]}. B held in VGPRs.
// Fragment layout (m89-verified): A row=lane&15, k=(lane>>4)*8+i (+32*k32);
// B col=lane&15, same k; C col=lane&15, row=(lane>>4)*4+reg.
__launch_bounds__(256)
__global__ void k_node_gemm(const float* __restrict__ nf,
                            const float* __restrict__ Wni,
                            const float* __restrict__ Wnj,
                            const float* __restrict__ Wnode,
                            float* __restrict__ fni,
                            float* __restrict__ fnj,
                            float* __restrict__ hproj,
                            int Nn) {
    int tid = threadIdx.x;
    int lane = tid & 63;
    int w = tid >> 6;
    int m = lane & 15;
    int kq = lane >> 4;
    const float* W; float* out; int wstride, wcoff, ostride, ocoff;
    if (w == 0)      { W = Wni;   wstride = 64;  wcoff = 0;  out = fni;   ostride = 64;  ocoff = 0; }
    else if (w == 1) { W = Wnj;   wstride = 64;  wcoff = 0;  out = fnj;   ostride = 64;  ocoff = 0; }
    else if (w == 2) { W = Wnode; wstride = 128; wcoff = 0;  out = hproj; ostride = 128; ocoff = 0; }
    else             { W = Wnode; wstride = 128; wcoff = 64; out = hproj; ostride = 128; ocoff = 64; }
    // B fragments: bv[k32][t], k = k32*32 + kq*8 + i, col = t*16 + m
    bf16x8 bv[4][4];
    #pragma unroll
    for (int k32 = 0; k32 < 4; k32++) {
        #pragma unroll
        for (int t = 0; t < 4; t++) {
            unsigned* bw = (unsigned*)&bv[k32][t];
            #pragma unroll
            for (int i = 0; i < 4; i++) {
                int k0 = k32 * 32 + kq * 8 + 2 * i;
                float lo = W[(size_t)k0 * wstride + wcoff + t * 16 + m];
                float hi = W[(size_t)(k0 + 1) * wstride + wcoff + t * 16 + m];
                bw[i] = cvt_pk_bf16(lo, hi);
            }
        }
    }
    int ngroups = (Nn + 15) >> 4;
    for (int g = blockIdx.x; g < ngroups; g += gridDim.x) {
        int r0 = g << 4;
        // A fragments: row r0+m, k-slice per k32
        int ra = r0 + m; if (ra >= Nn) ra = Nn - 1;
        const float* ap = &nf[(size_t)ra * INN + kq * 8];
        bf16x8 av[4];
        #pragma unroll
        for (int k32 = 0; k32 < 4; k32++) {
            float4 a0 = *(const float4*)(ap + k32 * 32);
            float4 a1 = *(const float4*)(ap + k32 * 32 + 4);
            unsigned* aw = (unsigned*)&av[k32];
            aw[0] = cvt_pk_bf16(a0.x, a0.y);
            aw[1] = cvt_pk_bf16(a0.z, a0.w);
            aw[2] = cvt_pk_bf16(a1.x, a1.y);
            aw[3] = cvt_pk_bf16(a1.z, a1.w);
        }
        f32x4 c[4];
        #pragma unroll
        for (int t = 0; t < 4; t++) {
            c[t] = (f32x4){0.f, 0.f, 0.f, 0.f};
            #pragma unroll
            for (int k32 = 0; k32 < 4; k32++)
                c[t] = __builtin_amdgcn_mfma_f32_16x16x32_bf16(av[k32], bv[k32][t], c[t], 0, 0, 0);
        }
        #pragma unroll
        for (int t = 0; t < 4; t++) {
            #pragma unroll
            for (int j = 0; j < 4; j++) {
                int gr = r0 + kq * 4 + j;
                if (gr < Nn) out[(size_t)gr * ostride + ocoff + t * 16 + m] = c[t][j];
            }
        }
    }
}

// ---------------- K2: edge pass — MFMA fij + gather clause + CSR fill --------
__launch_bounds__(256)
__global__ void k_edge(const float* __restrict__ efeats,
                       const int* __restrict__ src,
                       const int* __restrict__ dst,
                       const float* __restrict__ Wfij,   // [32][64]
                       const float* __restrict__ bias,   // [64]
                       const float* __restrict__ attn,   // [64]
                       const float* __restrict__ fni,
                       const float* __restrict__ fnj,
                       const int* __restrict__ offsets,  // [N+1]
                       int* __restrict__ cursor,         // [N]
                       int* __restrict__ eids,           // [E]
                       float* __restrict__ fout,         // [E,64]
                       float* __restrict__ exws,         // [E,4]
                       int Ee) {
    int tid = threadIdx.x;
    int lane = tid & 63;
    int m = lane & 15;
    int kq = lane >> 4;
    // B fragments (one-time)
    bf16x8 bv[4];
    #pragma unroll
    for (int t = 0; t < 4; t++) {
        unsigned* bw = (unsigned*)&bv[t];
        #pragma unroll
        for (int i = 0; i < 4; i++) {
            float lo = Wfij[(kq * 8 + 2 * i) * HOE + t * 16 + m];
            float hi = Wfij[(kq * 8 + 2 * i + 1) * HOE + t * 16 + m];
            bw[i] = cvt_pk_bf16(lo, hi);
        }
    }
    float bb[4], aa[4];
    #pragma unroll
    for (int t = 0; t < 4; t++) { bb[t] = bias[t * 16 + m]; aa[t] = attn[t * 16 + m]; }

    int wid = (blockIdx.x * 256 + tid) >> 6;
    int nw = (gridDim.x * 256) >> 6;
    for (int e0 = wid * 16; e0 < Ee; e0 += nw * 16) {
        // A loads (issue first)
        int ea = e0 + m; if (ea >= Ee) ea = Ee - 1;
        const float* ap = &efeats[(size_t)ea * INE + kq * 8];
        float4 a0 = *(const float4*)ap;
        float4 a1 = *(const float4*)(ap + 4);
        // edge meta for this lane's 4 epilogue edges
        int eq[4], sj[4], dj[4]; bool ok[4];
        #pragma unroll
        for (int j = 0; j < 4; j++) {
            int q = e0 + kq * 4 + j;
            ok[j] = q < Ee;
            int ec = ok[j] ? q : (Ee - 1);
            eq[j] = q; sj[j] = src[ec]; dj[j] = dst[ec];
        }
        // gather clause: all 32 fni/fnj values in flight at once
        float gni[4][4], gnj[4][4];
        #pragma unroll
        for (int j = 0; j < 4; j++) {
            const float* pi = &fni[(size_t)sj[j] * HOE + m];
            const float* pj = &fnj[(size_t)dj[j] * HOE + m];
            #pragma unroll
            for (int t = 0; t < 4; t++) {
                gni[j][t] = pi[t * 16];
                gnj[j][t] = pj[t * 16];
            }
        }
        // convert + MFMA while gathers land
        bf16x8 av;
        {
            unsigned* aw = (unsigned*)&av;
            aw[0] = cvt_pk_bf16(a0.x, a0.y);
            aw[1] = cvt_pk_bf16(a0.z, a0.w);
            aw[2] = cvt_pk_bf16(a1.x, a1.y);
            aw[3] = cvt_pk_bf16(a1.z, a1.w);
        }
        f32x4 c[4];
        #pragma unroll
        for (int t = 0; t < 4; t++) {
            c[t] = __builtin_amdgcn_mfma_f32_16x16x32_bf16(av, bv[t], (f32x4){0.f,0.f,0.f,0.f}, 0, 0, 0);
        }
        // epilogue
        #pragma unroll
        for (int j = 0; j < 4; j++) {
            #pragma unroll
            for (int t = 0; t < 4; t++) {
                int col = t * 16 + m;
                float fv = c[t][j] + gni[j][t] + gnj[j][t] + bb[t];
                fv = fv > 0.f ? fv : 0.01f * fv;          // leaky relu
                if (ok[j]) fout[(size_t)eq[j] * HOE + col] = fv;
                float pl = fv * aa[t];
                #pragma unroll
                for (int o = 8; o >= 1; o >>= 1) pl += __shfl_xor(pl, o, 16);
                if (ok[j] && m == 0) exws[(size_t)eq[j] * NH + t] = __expf(pl);
            }
            if (ok[j] && m == 0) {
                int p = atomicAdd(&cursor[dj[j]], 1);
                eids[offsets[dj[j]] + p] = eq[j];
            }
        }
    }
}

// ---------------- K3a: per-chunk exclusive scan (chunks of 256) --------------
__global__ void k_scan_chunks(const int* __restrict__ count,
                              int* __restrict__ chunkscan,
                              int* __restrict__ chunktot, int n) {
    __shared__ int tmp[256];
    int t = threadIdx.x;
    int i = blockIdx.x * 256 + t;
    int v = (i < n) ? count[i] : 0;
    tmp[t] = v;
    __syncthreads();
    for (int o = 1; o < 256; o <<= 1) {
        int x = (t >= o) ? tmp[t - o] : 0;
        __syncthreads();
        tmp[t] += x;
        __syncthreads();
    }
    if (i < n) chunkscan[i] = tmp[t] - v;
    if (t == 255) chunktot[blockIdx.x] = tmp[t];
}

// ---------------- K3b: scan chunk totals (single block) ----------------------
__global__ void k_scan_tot(const int* __restrict__ tot, int* __restrict__ base, int nc) {
    __shared__ int tmp[1024];
    int t = threadIdx.x;
    int v = (t < nc) ? tot[t] : 0;
    tmp[t] = v;
    __syncthreads();
    for (int o = 1; o < 1024; o <<= 1) {
        int x = (t >= o) ? tmp[t - o] : 0;
        __syncthreads();
        tmp[t] += x;
        __syncthreads();
    }
    if (t < nc) base[t] = tmp[t] - v;
}

// ---------------- K3c: final offsets ----------------------------------------
__global__ void k_offsets(const int* __restrict__ chunkscan,
                          const int* __restrict__ chunkbase,
                          int* __restrict__ offsets, int Nn, int Ee) {
    int i = blockIdx.x * blockDim.x + threadIdx.x;
    if (i < Nn) offsets[i] = chunkscan[i] + chunkbase[i >> 8];
    if (i == 0) offsets[Nn] = Ee;
}

// ---------------- K5: node-centric softmax + aggregation (single pass) -------
__launch_bounds__(256)
__global__ void k_node_out(const int* __restrict__ offsets,
                           const int* __restrict__ eids,
                           const int* __restrict__ srcv,
                           const float* __restrict__ exws,   // [E,4]
                           const float* __restrict__ hproj,  // [N,128]
                           float* __restrict__ hout,         // [N,128]
                           int Nn) {
    int lane = threadIdx.x & 63;
    int n = (blockIdx.x * 256 + threadIdx.x) >> 6;
    if (n >= Nn) return;
    int o0 = offsets[n], o1 = offsets[n + 1];
    int hi = lane >> 5;
    float s0 = 0.f, s1 = 0.f, s2 = 0.f, s3 = 0.f;
    float a0 = 0.f, a1 = 0.f;
    for (int i0 = o0; i0 < o1; i0 += 64) {
        int nb = min(64, o1 - i0);
        int ve = 0, vs = 0;
        if (lane < nb) {
            ve = eids[i0 + lane];
            vs = srcv[ve];
        }
        for (int j = 0; j < nb; j++) {
            int e = __builtin_amdgcn_readlane(ve, j);
            int s = __builtin_amdgcn_readlane(vs, j);
            float4 x = *(const float4*)&exws[(size_t)e * NH];
            s0 += x.x; s1 += x.y; s2 += x.z; s3 += x.w;
            float exl = (hi == 0) ? x.x : x.y;
            float exh = (hi == 0) ? x.z : x.w;
            a0 += hproj[(size_t)s * HON + lane] * exl;
            a1 += hproj[(size_t)s * HON + 64 + lane] * exh;
        }
    }
    float r0 = s0 > 0.f ? 1.f / s0 : 0.f;
    float r1 = s1 > 0.f ? 1.f / s1 : 0.f;
    float r2 = s2 > 0.f ? 1.f / s2 : 0.f;
    float r3 = s3 > 0.f ? 1.f / s3 : 0.f;
    float rlo = (hi == 0) ? r0 : r1;
    float rhi = (hi == 0) ? r2 : r3;
    hout[(size_t)n * HON + lane] = a0 * rlo;
    hout[(size_t)n * HON + 64 + lane] = a1 * rhi;
}

// ---------------- launcher ----------------
extern "C" void kernel_launch(void* const* d_in, const int* in_sizes, int n_in,
                              void* d_out, int out_size, void* d_ws, size_t ws_size,
                              hipStream_t stream) {
    const float* n_feats = (const float*)d_in[0];
    const float* e_feats = (const float*)d_in[1];
    const int*   src     = (const int*)d_in[2];
    const int*   dst     = (const int*)d_in[3];
    const float* W_ni    = (const float*)d_in[4];
    const float* W_nj    = (const float*)d_in[5];
    const float* W_fij   = (const float*)d_in[6];
    const float* bias_e  = (const float*)d_in[7];
    const float* attn    = (const float*)d_in[8];
    const float* W_node  = (const float*)d_in[9];

    const int Nn = in_sizes[0] / INN;
    const int Ee = in_sizes[2];

    float* hout = (float*)d_out;                       // [N,128]
    float* fout = (float*)d_out + (size_t)Nn * HON;    // [E,64]

    char* ws = (char*)d_ws;
    size_t off = 0;
    auto alloc = [&](size_t bytes) {
        size_t o = off;
        off = (off + bytes + 255) & ~(size_t)255;
        return o;
    };
    size_t o_fni   = alloc((size_t)Nn * HOE * 4);
    size_t o_fnj   = alloc((size_t)Nn * HOE * 4);
    size_t o_hproj = alloc((size_t)Nn * HON * 4);
    size_t o_exws  = alloc((size_t)Ee * NH * 4);
    size_t o_eids  = alloc((size_t)Ee * 4);
    size_t o_cnt2  = alloc((size_t)2 * Nn * 4);        // count | cursor
    size_t o_offs  = alloc((size_t)(Nn + 1) * 4);
    size_t o_cscan = alloc((size_t)Nn * 4);
    size_t o_cbase = alloc((size_t)1024 * 4);
    (void)ws_size;

    float* fni   = (float*)(ws + o_fni);
    float* fnj   = (float*)(ws + o_fnj);
    float* hproj = (float*)(ws + o_hproj);
    float* exws  = (float*)(ws + o_exws);
    int* eids    = (int*)(ws + o_eids);
    int* cnt2    = (int*)(ws + o_cnt2);
    int* count   = cnt2;
    int* cursor  = cnt2 + Nn;
    int* offsets = (int*)(ws + o_offs);
    int* cscan   = (int*)(ws + o_cscan);
    int* cbase   = (int*)(ws + o_cbase);

    int nchunks = (Nn + 255) / 256;

    k_zero_i32<<<(2 * Nn + 255) / 256, 256, 0, stream>>>(cnt2, 2 * Nn);

    k_count<<<2048, 256, 0, stream>>>(dst, count, Ee);

    k_node_gemm<<<1024, 256, 0, stream>>>(
        n_feats, W_ni, W_nj, W_node, fni, fnj, hproj, Nn);

    k_scan_chunks<<<nchunks, 256, 0, stream>>>(count, cscan, cbase, Nn);
    k_scan_tot<<<1, 1024, 0, stream>>>(cbase, cbase, nchunks);
    k_offsets<<<(Nn + 255) / 256, 256, 0, stream>>>(cscan, cbase, offsets, Nn, Ee);

    k_edge<<<8192, 256, 0, stream>>>(
        e_feats, src, dst, W_fij, bias_e, attn, fni, fnj,
        offsets, cursor, eids, fout, exws, Ee);

    k_node_out<<<(Nn + 3) / 4, 256, 0, stream>>>(
        offsets, eids, src, exws, hproj, hout, Nn);
}